// Round 10
// baseline (174.060 us; speedup 1.0000x reference)
//
#include <hip/hip_runtime.h>

typedef _Float16 f16x8 __attribute__((ext_vector_type(8)));
typedef float f32x4 __attribute__((ext_vector_type(4)));

#define EMB 768
#define LQ 128
#define LD 1024
#define NB 32

typedef const __attribute__((address_space(1))) char gas_char;
typedef __attribute__((address_space(3))) char las_char;

__device__ __forceinline__ void gload16(const void* g, void* l) {
    __builtin_amdgcn_global_load_lds((gas_char*)g, (las_char*)l, 16, 0, 0);
}

// 128B-row tiles: 8 chunks of 16B, XOR row&7. 0 bank conflicts measured (R7-R9).
#define SWZ(row, ch) ((row) * 64 + ((((ch) ^ ((row) & 7))) * 8))

#define BAR() asm volatile("s_barrier" ::: "memory")
#define LGKM0() do { asm volatile("s_waitcnt lgkmcnt(0)" ::: "memory"); \
                     __builtin_amdgcn_sched_barrier(0); } while (0)
#define VMW(N) asm volatile("s_waitcnt vmcnt(" #N ")" ::: "memory")

// ---------- f32 -> f16, 8 elems/thread (W only) ----------
__global__ void cvt8_kernel(const float* __restrict__ in, _Float16* __restrict__ out, int n8) {
    int i = blockIdx.x * 256 + threadIdx.x;
    if (i >= n8) return;
    const float4 a = ((const float4*)in)[2 * i];
    const float4 b = ((const float4*)in)[2 * i + 1];
    f16x8 o;
    o[0] = (_Float16)a.x; o[1] = (_Float16)a.y; o[2] = (_Float16)a.z; o[3] = (_Float16)a.w;
    o[4] = (_Float16)b.x; o[5] = (_Float16)b.y; o[6] = (_Float16)b.z; o[7] = (_Float16)b.w;
    ((f16x8*)out)[i] = o;
}

// ---------- VT[b][e][q] = query_embed[b][q][e] (f16) ----------
__global__ void make_vt_kernel(const float* __restrict__ Q, _Float16* __restrict__ VT) {
    int i = blockIdx.x * 256 + threadIdx.x;
    if (i >= NB * EMB * LQ) return;
    int q = i % LQ;
    int e = (i / LQ) % EMB;
    int b = i / (LQ * EMB);
    VT[i] = (_Float16)Q[((size_t)b * LQ + q) * EMB + e];
}

// Stage a 128-row x 64-hw f16 tile (256-thread version, r2-proven; attn only).
__device__ __forceinline__ void stage_tile(const _Float16* g, _Float16* l, int tid) {
#pragma unroll
    for (int i = 0; i < 4; ++i) {
        const int idx = i * 256 + tid;
        const int row = idx >> 3, ch = idx & 7;
        gload16(g + (size_t)row * EMB + ((ch ^ (row & 7)) * 8), l + (size_t)idx * 8);
    }
}

// ---------- 256x128 4-phase projection GEMM, A read DIRECTLY as f32 ----------
// OUT[m,h] = relu(A[m,:].W[h,:]+bias[h]) f16. M=36864 (doc rows 0..32767, query
// 32768..36863 from separate f32 inputs), N=768, K=768. 512 thr = 8 waves
// (wr 0-1 x wc 0-3); per-wave out 128x32; acc[8][2]=64. BK=64, 12 K-tiles,
// 6 iters x 2 K-tiles (slot0/slot1). LDS 96KB: A slots 2x16384hw @0, B slots
// 2x8192hw @32768. A: f32 global->regs (linear, coalesced) -> cvt -> swizzled
// ds_write. B: gload_lds (inverse-swizzled source, linear dest).
//
// LEDGER (per-wave vmcnt; invariant: every staged tile retired/drained BEFORE a
// barrier that precedes any read of it — R9's proven rule):
//  prologue: issueA(0)[8] stageB(0,s0)[+2] VMW(2)(ret A0; B0 may remain)
//            writeA(s0) issueA(1)[8] stageB(1,s1)[+2] VMW(2)(ret B0+A1; leaves B1)
//            lgkm0 BAR.   entering j=0: [B(1)2], fA2=A(1) retired, s0 ready.
//  P1: writeA(fA2->s1-A=A(2j+1)) (region free since j-1 P4; drained by P1 LGKM0);
//      issue fA=A(2j+2), fA2=A(2j+3) [+16]; readB(s0)+readA(s0,MH0)
//      (s0-B retired at j-1 P4 VMW(2)+BAR; s0-A written j-1 P3+drain).
//  P2: readA(s0,MH1); stageB(2j+2->s0-B)[+2] (s0-B free after P1 reads+LGKM0);
//      VMW(18) -> retires B(2j+1) (oldest; <=20 outstanding) before P3 reads it.
//  P3: VMW(10) -> retires fA(2j+2) (compiler dep-waits back this up);
//      writeA(fA->s0-A) (region free after P2 reads); readB(s1)+readA(s1,MH0).
//  P4: readA(s1,MH1); stageB(2j+3->s1-B)[+2] (region free after P3 reads);
//      VMW(2) -> retires fA2+B(2j+2), leaves B(2j+3) -> invariant for j+1.
//  tail j=5: no issues/stages; P2 VMW(0) retires B(11) before P3 reads it.
__global__ __launch_bounds__(512, 2) void proj8f_kernel(
    const float* __restrict__ doc, const float* __restrict__ query,
    const _Float16* __restrict__ W16, const float* __restrict__ bias,
    _Float16* __restrict__ OUT) {
    extern __shared__ _Float16 smem[];  // 49152 hw = 96 KB
    const int tid = threadIdx.x, wave = tid >> 6, lane = tid & 63;
    const int lr = lane & 15, lkg = lane >> 4;
    const int wr = wave >> 2, wc = wave & 3;

    // XCD swizzle, col-fastest (864 % 8 == 0): A row-stripe reused by 6
    // consecutive same-XCD blocks (f32 stripe 786KB -> L2-resident).
    const int nwg = gridDim.x, cpx = nwg >> 3;
    const int swz = (blockIdx.x & 7) * cpx + (blockIdx.x >> 3);
    const int rowblk = swz / 6, colblk = swz - rowblk * 6;
    const int row0 = rowblk * 256, col0 = colblk * 128;

    const float* gAf = (rowblk < 128) ? doc + (size_t)row0 * EMB
                                      : query + (size_t)(row0 - 32768) * EMB;
    const _Float16* gB = W16 + (size_t)col0 * EMB;

    // A staging coords: 4 chunks/thread (256x64 f16 = 2048 16B-chunks / 512 thr)
    int arow[4], ach[4];
#pragma unroll
    for (int w = 0; w < 4; ++w) {
        const int cidx = w * 512 + tid;
        arow[w] = cidx >> 3; ach[w] = cidx & 7;
    }
    // B staging coords: 2 chunks/thread (128x64 f16 = 1024 chunks / 512 thr)
    int brow[2], bch[2];
#pragma unroll
    for (int w = 0; w < 2; ++w) {
        const int idx = w * 512 + tid;
        brow[w] = idx >> 3; bch[w] = idx & 7;
    }

#define ISSUE_A(kt, f) do { _Pragma("unroll") for (int w_ = 0; w_ < 4; ++w_) { \
        const float* s_ = gAf + (size_t)arow[w_] * EMB + (kt) * 64 + ach[w_] * 8; \
        f[w_][0] = *(const float4*)s_; f[w_][1] = *(const float4*)(s_ + 4); } } while (0)

#define WRITE_A(slot, f) do { _Pragma("unroll") for (int w_ = 0; w_ < 4; ++w_) { \
        f16x8 v_; \
        v_[0] = (_Float16)f[w_][0].x; v_[1] = (_Float16)f[w_][0].y; \
        v_[2] = (_Float16)f[w_][0].z; v_[3] = (_Float16)f[w_][0].w; \
        v_[4] = (_Float16)f[w_][1].x; v_[5] = (_Float16)f[w_][1].y; \
        v_[6] = (_Float16)f[w_][1].z; v_[7] = (_Float16)f[w_][1].w; \
        const int half_ = arow[w_] >> 7, lrow_ = arow[w_] & 127; \
        *(f16x8*)(smem + (slot) * 16384 + half_ * 8192 + SWZ(lrow_, ach[w_])) = v_; } } while (0)

#define STAGE_B(kt, slot) do { _Pragma("unroll") for (int w_ = 0; w_ < 2; ++w_) \
        gload16(gB + (size_t)brow[w_] * EMB + (kt) * 64 + ((bch[w_] ^ (brow[w_] & 7)) * 8), \
                smem + 32768 + (slot) * 8192 + (size_t)(w_ * 512 + tid) * 8); } while (0)

    f32x4 acc[8][2];
#pragma unroll
    for (int m = 0; m < 8; ++m)
#pragma unroll
        for (int n = 0; n < 2; ++n) acc[m][n] = (f32x4){0.f, 0.f, 0.f, 0.f};

    f16x8 aF[4][2], bF[2][2];

#define READ_A(slot, MH) do { const _Float16* ab_ = smem + (slot) * 16384 + wr * 8192; \
    _Pragma("unroll") for (int mm = 0; mm < 4; ++mm) _Pragma("unroll") for (int ks = 0; ks < 2; ++ks) \
        aF[mm][ks] = *(const f16x8*)(ab_ + SWZ(((MH) * 4 + mm) * 16 + lr, ks * 4 + lkg)); } while (0)
#define READ_B(slot) do { const _Float16* bb_ = smem + 32768 + (slot) * 8192; \
    _Pragma("unroll") for (int nn = 0; nn < 2; ++nn) _Pragma("unroll") for (int ks = 0; ks < 2; ++ks) \
        bF[nn][ks] = *(const f16x8*)(bb_ + SWZ(wc * 32 + nn * 16 + lr, ks * 4 + lkg)); } while (0)
#define MFMA_H(MH) do { __builtin_amdgcn_s_setprio(1); \
    _Pragma("unroll") for (int mm = 0; mm < 4; ++mm) _Pragma("unroll") for (int nn = 0; nn < 2; ++nn) \
    _Pragma("unroll") for (int ks = 0; ks < 2; ++ks) \
        acc[(MH) * 4 + mm][nn] = __builtin_amdgcn_mfma_f32_16x16x32_f16( \
            aF[mm][ks], bF[nn][ks], acc[(MH) * 4 + mm][nn], 0, 0, 0); \
    __builtin_amdgcn_s_setprio(0); } while (0)

    float4 fA[4][2], fA2[4][2];

    // ---- prologue ----
    ISSUE_A(0, fA);
    STAGE_B(0, 0);
    VMW(2);
    WRITE_A(0, fA);
    ISSUE_A(1, fA2);
    STAGE_B(1, 1);
    VMW(2);
    asm volatile("s_waitcnt lgkmcnt(0)" ::: "memory");
    BAR();

#pragma unroll 1
    for (int j = 0; j < 6; ++j) {
        const int kt2 = 2 * j + 2, kt3 = 2 * j + 3;
        // ---- P1: slot0, MH0 ----
        WRITE_A(1, fA2);
        if (j < 5) { ISSUE_A(kt2, fA); ISSUE_A(kt3, fA2); }
        READ_B(0); READ_A(0, 0);
        BAR(); LGKM0(); MFMA_H(0); BAR();
        // ---- P2: slot0, MH1 ----
        READ_A(0, 1);
        if (j < 5) { STAGE_B(kt2, 0); VMW(18); }
        else       { VMW(0); }
        BAR(); LGKM0(); MFMA_H(1); BAR();
        // ---- P3: slot1, MH0 ----
        VMW(10);
        if (j < 5) WRITE_A(0, fA);
        READ_B(1); READ_A(1, 0);
        BAR(); LGKM0(); MFMA_H(0); BAR();
        // ---- P4: slot1, MH1 ----
        READ_A(1, 1);
        if (j < 5) STAGE_B(kt3, 1);
        VMW(2);
        BAR(); LGKM0(); MFMA_H(1); BAR();
    }

    // epilogue: bias + ReLU + f16 store
    const int crow = lkg * 4;
#pragma unroll
    for (int n = 0; n < 2; ++n) {
        const int gc = col0 + wc * 32 + n * 16 + lr;
        const float bv = bias[gc];
#pragma unroll
        for (int m = 0; m < 8; ++m) {
            const size_t gr = (size_t)row0 + wr * 128 + m * 16 + crow;
#pragma unroll
            for (int r = 0; r < 4; ++r) {
                float v = acc[m][n][r] + bv;
                OUT[(gr + r) * EMB + gc] = (_Float16)(v > 0.f ? v : 0.f);
            }
        }
    }
#undef ISSUE_A
#undef WRITE_A
#undef STAGE_B
#undef READ_A
#undef READ_B
#undef MFMA_H
}

// ---------- attention: 128 doc rows/block (r2-proven, verbatim) ----------
__global__ __launch_bounds__(256) void attn128_kernel(
    const _Float16* __restrict__ Do, const _Float16* __restrict__ Qo,
    const _Float16* __restrict__ VT, float* __restrict__ OUT) {
    __shared__ __align__(16) _Float16 smem[32768];
    const int tid = threadIdx.x, wave = tid >> 6, lane = tid & 63;
    const int lr = lane & 15, lkg = lane >> 4;
    const int b = blockIdx.x, dblk = blockIdx.y;
    const _Float16* gd = Do + ((size_t)b * LD + dblk * 128) * EMB;
    const _Float16* gq = Qo + (size_t)b * LQ * EMB;

    f32x4 s[2][8];
#pragma unroll
    for (int m = 0; m < 2; ++m)
#pragma unroll
        for (int n = 0; n < 8; ++n) s[m][n] = (f32x4){0.f, 0.f, 0.f, 0.f};

    stage_tile(gd, smem, tid);
    stage_tile(gq, smem + 8192, tid);
    int cur = 0;
    for (int it = 0; it < 12; ++it) {
        __syncthreads();
        if (it < 11) {
            stage_tile(gd + (it + 1) * 64, smem + (cur ^ 1) * 16384, tid);
            stage_tile(gq + (it + 1) * 64, smem + (cur ^ 1) * 16384 + 8192, tid);
        }
        const _Float16* sD = smem + cur * 16384;
        const _Float16* sQ = sD + 8192;
#pragma unroll
        for (int kk = 0; kk < 2; ++kk) {
            const int ch = kk * 4 + lkg;
            f16x8 am[2];
#pragma unroll
            for (int m = 0; m < 2; ++m)
                am[m] = *(const f16x8*)(sD + SWZ(wave * 32 + m * 16 + lr, ch));
#pragma unroll
            for (int n = 0; n < 8; ++n) {
                const f16x8 bq = *(const f16x8*)(sQ + SWZ(n * 16 + lr, ch));
#pragma unroll
                for (int m = 0; m < 2; ++m)
                    s[m][n] = __builtin_amdgcn_mfma_f32_16x16x32_f16(am[m], bq, s[m][n], 0, 0, 0);
            }
        }
        cur ^= 1;
    }
    __syncthreads();

    _Float16 (*P)[136] = (_Float16 (*)[136])smem;
    const int crow = lkg * 4;
#pragma unroll
    for (int m = 0; m < 2; ++m) {
#pragma unroll
        for (int r = 0; r < 4; ++r) {
            float mx = -1e30f;
#pragma unroll
            for (int n = 0; n < 8; ++n) mx = fmaxf(mx, s[m][n][r]);
#pragma unroll
            for (int off = 1; off < 16; off <<= 1) mx = fmaxf(mx, __shfl_xor(mx, off));
            float p[8], sum = 0.f;
#pragma unroll
            for (int n = 0; n < 8; ++n) { p[n] = __expf(s[m][n][r] - mx); sum += p[n]; }
#pragma unroll
            for (int off = 1; off < 16; off <<= 1) sum += __shfl_xor(sum, off);
            const float inv = 1.f / sum;
            const int row = wave * 32 + m * 16 + crow + r;
#pragma unroll
            for (int n = 0; n < 8; ++n) P[row][n * 16 + lr] = (_Float16)(p[n] * inv);
        }
    }
    __syncthreads();

    const _Float16* vtb = VT + (size_t)b * EMB * LQ;
#pragma unroll 1
    for (int nc = 0; nc < 6; ++nc) {
        f32x4 o[2][8];
#pragma unroll
        for (int m = 0; m < 2; ++m)
#pragma unroll
            for (int t = 0; t < 8; ++t) o[m][t] = (f32x4){0.f, 0.f, 0.f, 0.f};
#pragma unroll
        for (int ks = 0; ks < 4; ++ks) {
            f16x8 am[2];
#pragma unroll
            for (int m = 0; m < 2; ++m)
                am[m] = *(const f16x8*)(&P[wave * 32 + m * 16 + lr][ks * 32 + lkg * 8]);
#pragma unroll
            for (int t = 0; t < 8; ++t) {
                const f16x8 bv = *(const f16x8*)(vtb + (size_t)(nc * 128 + t * 16 + lr) * LQ + ks * 32 + lkg * 8);
#pragma unroll
                for (int m = 0; m < 2; ++m)
                    o[m][t] = __builtin_amdgcn_mfma_f32_16x16x32_f16(am[m], bv, o[m][t], 0, 0, 0);
            }
        }
#pragma unroll
        for (int t = 0; t < 8; ++t) {
#pragma unroll
            for (int m = 0; m < 2; ++m) {
                const size_t gr = (size_t)b * LD + dblk * 128 + wave * 32 + m * 16 + crow;
                const int e = nc * 128 + t * 16 + lr;
#pragma unroll
                for (int r = 0; r < 4; ++r)
                    OUT[(gr + r) * EMB + e] = o[m][t][r];
            }
        }
    }
}

extern "C" void kernel_launch(void* const* d_in, const int* in_sizes, int n_in,
                              void* d_out, int out_size, void* d_ws, size_t ws_size,
                              hipStream_t stream) {
    const float* doc   = (const float*)d_in[0];   // [32,1024,768]
    const float* query = (const float*)d_in[1];   // [32,128,768]
    const float* W     = (const float*)d_in[2];   // [768,768]
    const float* bias  = (const float*)d_in[3];   // [768]
    float* out = (float*)d_out;                   // [32,1024,768] f32

    const size_t nW  = (size_t)EMB * EMB;        // 589824
    const size_t nVT = (size_t)NB * EMB * LQ;    // 3145728
    const size_t nDo = (size_t)NB * LD * EMB;    // 25165824
    const size_t nQo = (size_t)NB * LQ * EMB;    // 3145728
    const size_t need = (nW + nVT + nDo + nQo) * sizeof(_Float16);  // ~64.1 MB (proven fits)
    if (ws_size < need) return;

    _Float16* W16 = (_Float16*)d_ws;
    _Float16* VT  = W16 + nW;
    _Float16* Do  = VT + nVT;    // Do || Qo contiguous: merged proj output
    _Float16* Qo  = Do + nDo;

    cvt8_kernel<<<(int)(nW / 8 / 256), 256, 0, stream>>>(W, W16, (int)(nW / 8));
    make_vt_kernel<<<(int)(nVT / 256), 256, 0, stream>>>(query, VT);

    // merged projection reading f32 activations directly:
    // M = 36864 -> 144 rowblks x 6 colblks = 864 blocks (%8==0), 96KB LDS
    hipFuncSetAttribute(reinterpret_cast<const void*>(&proj8f_kernel),
                        hipFuncAttributeMaxDynamicSharedMemorySize, 98304);
    proj8f_kernel<<<dim3(144 * 6), 512, 98304, stream>>>(doc, query, W16, bias, Do);

    attn128_kernel<<<dim3(NB, LD / 128), 256, 0, stream>>>(Do, Qo, VT, out);
}

// Round 11
// 150.842 us; speedup vs baseline: 1.1539x; 1.1539x over previous
//
#include <hip/hip_runtime.h>

typedef _Float16 f16x8 __attribute__((ext_vector_type(8)));
typedef _Float16 f16x4 __attribute__((ext_vector_type(4)));
typedef float f32x4 __attribute__((ext_vector_type(4)));

#define EMB 768
#define LQ 128
#define LD 1024
#define NB 32

typedef const __attribute__((address_space(1))) char gas_char;
typedef __attribute__((address_space(3))) char las_char;

__device__ __forceinline__ void gload16(const void* g, void* l) {
    __builtin_amdgcn_global_load_lds((gas_char*)g, (las_char*)l, 16, 0, 0);
}

// 128B-row tiles: 8 chunks of 16B, XOR row&7. 0 bank conflicts measured (R7-R9).
#define SWZ(row, ch) ((row) * 64 + ((((ch) ^ ((row) & 7))) * 8))

#define BAR() asm volatile("s_barrier" ::: "memory")
#define LGKM0() do { asm volatile("s_waitcnt lgkmcnt(0)" ::: "memory"); \
                     __builtin_amdgcn_sched_barrier(0); } while (0)
#define VMW(N) asm volatile("s_waitcnt vmcnt(" #N ")" ::: "memory")

// ---------- f32 -> f16, 8 elems/thread ----------
__global__ void cvt8_kernel(const float* __restrict__ in, _Float16* __restrict__ out, int n8) {
    int i = blockIdx.x * 256 + threadIdx.x;
    if (i >= n8) return;
    const float4 a = ((const float4*)in)[2 * i];
    const float4 b = ((const float4*)in)[2 * i + 1];
    f16x8 o;
    o[0] = (_Float16)a.x; o[1] = (_Float16)a.y; o[2] = (_Float16)a.z; o[3] = (_Float16)a.w;
    o[4] = (_Float16)b.x; o[5] = (_Float16)b.y; o[6] = (_Float16)b.z; o[7] = (_Float16)b.w;
    ((f16x8*)out)[i] = o;
}

// ---------- VT[b][e][q] = Q[b][q][e] via LDS tile transpose (coalesced both sides) ----
// grid (2, 12, 32): q-tile 64, e-tile 64, batch. Block 256.
__global__ __launch_bounds__(256) void make_vt_kernel(const float* __restrict__ Q,
                                                      _Float16* __restrict__ VT) {
    __shared__ float t[64][65];  // pad -> transpose reads 2-way (free)
    const int tid = threadIdx.x;
    const int q0 = blockIdx.x * 64, e0 = blockIdx.y * 64, b = blockIdx.z;
    const int rr = tid >> 4, cc = (tid & 15) * 4;
#pragma unroll
    for (int i = 0; i < 4; ++i) {
        const int row = i * 16 + rr;  // q-row
        const float4 v = *(const float4*)(Q + ((size_t)b * LQ + q0 + row) * EMB + e0 + cc);
        t[row][cc + 0] = v.x; t[row][cc + 1] = v.y; t[row][cc + 2] = v.z; t[row][cc + 3] = v.w;
    }
    __syncthreads();
#pragma unroll
    for (int i = 0; i < 4; ++i) {
        const int erow = i * 16 + rr;
        f16x4 v;
#pragma unroll
        for (int j = 0; j < 4; ++j) v[j] = (_Float16)t[cc + j][erow];
        *(f16x4*)(VT + ((size_t)b * EMB + e0 + erow) * LQ + q0 + cc) = v;
    }
}

// Stage a 128-row x 64-hw f16 tile (256 threads, r2-proven).
__device__ __forceinline__ void stage_tile(const _Float16* g, _Float16* l, int tid) {
#pragma unroll
    for (int i = 0; i < 4; ++i) {
        const int idx = i * 256 + tid;
        const int row = idx >> 3, ch = idx & 7;
        gload16(g + (size_t)row * EMB + ((ch ^ (row & 7)) * 8), l + (size_t)idx * 8);
    }
}

// Stage a 64-row x 64-hw f16 tile (256 threads).
__device__ __forceinline__ void stage_d64(const _Float16* g, _Float16* l, int tid) {
#pragma unroll
    for (int i = 0; i < 2; ++i) {
        const int idx = i * 256 + tid;
        const int row = idx >> 3, ch = idx & 7;
        gload16(g + (size_t)row * EMB + ((ch ^ (row & 7)) * 8), l + (size_t)idx * 8);
    }
}

// ---------- 256x256 8-phase projection GEMM (R9-proven, verbatim) ----------
// VMCNT LEDGER: see R9 — prologue leaves kt1's 8 in flight after VMW(8); per iter
// stages at P3/P4/P7/P8 with VMW(4) only at P4/P8; tail drains VMW(0) at P4.
__global__ __launch_bounds__(512, 2) void proj8_kernel(
    const _Float16* __restrict__ A, const _Float16* __restrict__ W16,
    const float* __restrict__ bias, _Float16* __restrict__ OUT) {
    extern __shared__ _Float16 smem[];  // 65536 hw = 128 KB
    const int tid = threadIdx.x, wave = tid >> 6, lane = tid & 63;
    const int lr = lane & 15, lkg = lane >> 4;
    const int wr = wave >> 2, wc = wave & 3;

    const int nwg = gridDim.x, cpx = nwg >> 3;
    const int swz = (blockIdx.x & 7) * cpx + (blockIdx.x >> 3);
    const int rowblk = swz / 3, colblk = swz - rowblk * 3;
    const int row0 = rowblk * 256, col0 = colblk * 256;

    const int r0_ = tid >> 3, c0_ = (((tid & 7) ^ (r0_ & 7)) * 8);
    const int r1_ = (512 + tid) >> 3, c1_ = ((((512 + tid) & 7) ^ (r1_ & 7)) * 8);
    const int lo0 = tid * 8, lo1 = (512 + tid) * 8;

    const _Float16* gA0 = A + (size_t)row0 * EMB;
    const _Float16* gA1 = A + (size_t)(row0 + 128) * EMB;
    const _Float16* gB0 = W16 + (size_t)col0 * EMB;
    const _Float16* gB1 = W16 + (size_t)(col0 + 128) * EMB;

#define STAGE_PAIR(g0, g1, kt, lbase) do { \
    const _Float16* s0_ = (g0) + (kt) * 64; const _Float16* s1_ = (g1) + (kt) * 64; \
    _Float16* d_ = (lbase); \
    gload16(s0_ + (size_t)r0_ * EMB + c0_, d_ + lo0); \
    gload16(s0_ + (size_t)r1_ * EMB + c1_, d_ + lo1); \
    gload16(s1_ + (size_t)r0_ * EMB + c0_, d_ + 8192 + lo0); \
    gload16(s1_ + (size_t)r1_ * EMB + c1_, d_ + 8192 + lo1); } while (0)

    f32x4 acc[8][4];
#pragma unroll
    for (int m = 0; m < 8; ++m)
#pragma unroll
        for (int n = 0; n < 4; ++n) acc[m][n] = (f32x4){0.f, 0.f, 0.f, 0.f};

    f16x8 aF[4][2], bF[4][2];
    const int bro = (wc & 1) * 64;

#define READ_A(slot, MH) do { _Float16* ab_ = smem + (slot) * 32768 + wr * 8192; \
    _Pragma("unroll") for (int mm = 0; mm < 4; ++mm) _Pragma("unroll") for (int ks = 0; ks < 2; ++ks) \
        aF[mm][ks] = *(const f16x8*)(ab_ + SWZ(((MH) * 4 + mm) * 16 + lr, ks * 4 + lkg)); } while (0)
#define READ_B(slot, NH) do { _Float16* bb_ = smem + (slot) * 32768 + 16384 + (wc >> 1) * 8192; \
    _Pragma("unroll") for (int nn = 0; nn < 2; ++nn) _Pragma("unroll") for (int ks = 0; ks < 2; ++ks) \
        bF[(NH) * 2 + nn][ks] = *(const f16x8*)(bb_ + SWZ(bro + ((NH) * 2 + nn) * 16 + lr, ks * 4 + lkg)); } while (0)
#define MFMA_Q(MH, NH) do { __builtin_amdgcn_s_setprio(1); \
    _Pragma("unroll") for (int mm = 0; mm < 4; ++mm) _Pragma("unroll") for (int nn = 0; nn < 2; ++nn) \
    _Pragma("unroll") for (int ks = 0; ks < 2; ++ks) \
        acc[(MH) * 4 + mm][(NH) * 2 + nn] = __builtin_amdgcn_mfma_f32_16x16x32_f16( \
            aF[mm][ks], bF[(NH) * 2 + nn][ks], acc[(MH) * 4 + mm][(NH) * 2 + nn], 0, 0, 0); \
    __builtin_amdgcn_s_setprio(0); } while (0)

    STAGE_PAIR(gB0, gB1, 0, smem + 16384);
    STAGE_PAIR(gA0, gA1, 0, smem);
    STAGE_PAIR(gB0, gB1, 1, smem + 32768 + 16384);
    STAGE_PAIR(gA0, gA1, 1, smem + 32768);
    VMW(8);
    BAR();

#pragma unroll 1
    for (int j = 0; j < 6; ++j) {
        const int kt2 = 2 * j + 2, kt3 = 2 * j + 3;
        READ_B(0, 0); READ_B(0, 1); READ_A(0, 0);
        BAR(); LGKM0(); MFMA_Q(0, 0); BAR();
        BAR(); LGKM0(); MFMA_Q(0, 1); BAR();
        READ_A(0, 1);
        if (j < 5) STAGE_PAIR(gB0, gB1, kt2, smem + 16384);
        BAR(); LGKM0(); MFMA_Q(1, 0); BAR();
        if (j < 5) { STAGE_PAIR(gA0, gA1, kt2, smem); VMW(4); }
        else       { VMW(0); }
        BAR(); LGKM0(); MFMA_Q(1, 1); BAR();
        READ_B(1, 0); READ_B(1, 1); READ_A(1, 0);
        BAR(); LGKM0(); MFMA_Q(0, 0); BAR();
        BAR(); LGKM0(); MFMA_Q(0, 1); BAR();
        READ_A(1, 1);
        if (j < 5) STAGE_PAIR(gB0, gB1, kt3, smem + 32768 + 16384);
        BAR(); LGKM0(); MFMA_Q(1, 0); BAR();
        if (j < 5) { STAGE_PAIR(gA0, gA1, kt3, smem + 32768); VMW(4); }
        BAR(); LGKM0(); MFMA_Q(1, 1); BAR();
    }

    const int crow = lkg * 4;
#pragma unroll
    for (int n = 0; n < 4; ++n) {
        const int gc = col0 + wc * 64 + n * 16 + lr;
        const float bv = bias[gc];
#pragma unroll
        for (int m = 0; m < 8; ++m) {
            const size_t gr = (size_t)row0 + wr * 128 + m * 16 + crow;
#pragma unroll
            for (int r = 0; r < 4; ++r) {
                float v = acc[m][n][r] + bv;
                OUT[(gr + r) * EMB + gc] = (_Float16)(v > 0.f ? v : 0.f);
            }
        }
    }
#undef STAGE_PAIR
#undef READ_A
#undef READ_B
#undef MFMA_Q
}

// ---------- attention: 64 doc rows/block, 512 blocks = 2 generations/CU ----------
// 4 waves x 16 rows. LDS 48KB (dbuf x [D 4096 | Q 8192]); P[64][136] aliases after.
// Batch-locality XCD swizzle (R3-proven): XCD x owns batches 4x..4x+3.
__global__ __launch_bounds__(256) void attn64_kernel(
    const _Float16* __restrict__ Do, const _Float16* __restrict__ Qo,
    const _Float16* __restrict__ VT, float* __restrict__ OUT) {
    __shared__ __align__(16) _Float16 smem[24576];
    const int tid = threadIdx.x, wave = tid >> 6, lane = tid & 63;
    const int lr = lane & 15, lkg = lane >> 4;

    const int l = blockIdx.x;             // 0..511
    const int x = l & 7, i = l >> 3;      // i: 0..63
    const int b = x * 4 + (i >> 4), dblk = i & 15;

    const _Float16* gd = Do + ((size_t)b * LD + dblk * 64) * EMB;
    const _Float16* gq = Qo + (size_t)b * LQ * EMB;

    f32x4 s[8];
#pragma unroll
    for (int n = 0; n < 8; ++n) s[n] = (f32x4){0.f, 0.f, 0.f, 0.f};

    stage_d64(gd, smem, tid);
    stage_tile(gq, smem + 4096, tid);
    int cur = 0;
    for (int it = 0; it < 12; ++it) {
        __syncthreads();
        if (it < 11) {
            stage_d64(gd + (it + 1) * 64, smem + (cur ^ 1) * 12288, tid);
            stage_tile(gq + (it + 1) * 64, smem + (cur ^ 1) * 12288 + 4096, tid);
        }
        const _Float16* sD = smem + cur * 12288;
        const _Float16* sQ = sD + 4096;
#pragma unroll
        for (int kk = 0; kk < 2; ++kk) {
            const int ch = kk * 4 + lkg;
            const f16x8 am = *(const f16x8*)(sD + SWZ(wave * 16 + lr, ch));
#pragma unroll
            for (int n = 0; n < 8; ++n) {
                const f16x8 bq = *(const f16x8*)(sQ + SWZ(n * 16 + lr, ch));
                s[n] = __builtin_amdgcn_mfma_f32_16x16x32_f16(am, bq, s[n], 0, 0, 0);
            }
        }
        cur ^= 1;
    }
    __syncthreads();  // staging reads done before P overwrites smem

    _Float16 (*P)[136] = (_Float16 (*)[136])smem;  // 64x136 = 8704 hw (fits)
    const int crow = lkg * 4;
#pragma unroll
    for (int r = 0; r < 4; ++r) {
        float mx = -1e30f;
#pragma unroll
        for (int n = 0; n < 8; ++n) mx = fmaxf(mx, s[n][r]);
#pragma unroll
        for (int off = 1; off < 16; off <<= 1) mx = fmaxf(mx, __shfl_xor(mx, off));
        float p[8], sum = 0.f;
#pragma unroll
        for (int n = 0; n < 8; ++n) { p[n] = __expf(s[n][r] - mx); sum += p[n]; }
#pragma unroll
        for (int off = 1; off < 16; off <<= 1) sum += __shfl_xor(sum, off);
        const float inv = 1.f / sum;
        const int row = wave * 16 + crow + r;
#pragma unroll
        for (int n = 0; n < 8; ++n) P[row][n * 16 + lr] = (_Float16)(p[n] * inv);
    }
    __syncthreads();

    const _Float16* vtb = VT + (size_t)b * EMB * LQ;
    const size_t dbase = (size_t)b * LD + dblk * 64 + wave * 16 + crow;
#pragma unroll 1
    for (int nc = 0; nc < 6; ++nc) {
        f32x4 o[8];
#pragma unroll
        for (int t = 0; t < 8; ++t) o[t] = (f32x4){0.f, 0.f, 0.f, 0.f};
#pragma unroll
        for (int ks = 0; ks < 4; ++ks) {
            const f16x8 am = *(const f16x8*)(&P[wave * 16 + lr][ks * 32 + lkg * 8]);
#pragma unroll
            for (int t = 0; t < 8; ++t) {
                const f16x8 bv = *(const f16x8*)(vtb + (size_t)(nc * 128 + t * 16 + lr) * LQ
                                                 + ks * 32 + lkg * 8);
                o[t] = __builtin_amdgcn_mfma_f32_16x16x32_f16(am, bv, o[t], 0, 0, 0);
            }
        }
#pragma unroll
        for (int t = 0; t < 8; ++t) {
            const int e = nc * 128 + t * 16 + lr;
#pragma unroll
            for (int r = 0; r < 4; ++r)
                OUT[(dbase + r) * EMB + e] = o[t][r];
        }
    }
}

extern "C" void kernel_launch(void* const* d_in, const int* in_sizes, int n_in,
                              void* d_out, int out_size, void* d_ws, size_t ws_size,
                              hipStream_t stream) {
    const float* doc   = (const float*)d_in[0];   // [32,1024,768]
    const float* query = (const float*)d_in[1];   // [32,128,768]
    const float* W     = (const float*)d_in[2];   // [768,768]
    const float* bias  = (const float*)d_in[3];   // [768]
    float* out = (float*)d_out;                   // [32,1024,768] f32

    const size_t nW  = (size_t)EMB * EMB;        // 589824
    const size_t nVT = (size_t)NB * EMB * LQ;    // 3145728
    const size_t nDo = (size_t)NB * LD * EMB;    // 25165824
    const size_t nQo = (size_t)NB * LQ * EMB;    // 3145728
    const size_t need = (nW + nVT + nDo + nQo) * sizeof(_Float16);  // ~64.1 MB
    if (ws_size < need) return;

    _Float16* W16 = (_Float16*)d_ws;
    _Float16* VT  = W16 + nW;
    _Float16* Do  = VT + nVT;    // Do || Qo contiguous: merged proj output
    _Float16* Qo  = Do + nDo;

    // f16 doc||query contiguous in d_out (dead until attn overwrites it)
    _Float16* doc16 = (_Float16*)d_out;
    _Float16* q16   = doc16 + nDo;

    cvt8_kernel<<<(int)(nDo / 8 / 256), 256, 0, stream>>>(doc, doc16, (int)(nDo / 8));
    cvt8_kernel<<<(int)(nQo / 8 / 256), 256, 0, stream>>>(query, q16, (int)(nQo / 8));
    cvt8_kernel<<<(int)(nW / 8 / 256), 256, 0, stream>>>(W, W16, (int)(nW / 8));
    make_vt_kernel<<<dim3(2, 12, NB), 256, 0, stream>>>(query, VT);

    // merged projection: M = 36864 -> 144 rowblks x 3 colblks = 432 blocks, 128KB LDS
    hipFuncSetAttribute(reinterpret_cast<const void*>(&proj8_kernel),
                        hipFuncAttributeMaxDynamicSharedMemorySize, 131072);
    proj8_kernel<<<dim3(144 * 3), 512, 131072, stream>>>(doc16, W16, bias, Do);

    attn64_kernel<<<dim3(NB * 16), 256, 0, stream>>>(Do, Qo, VT, out);
}